// Round 5
// baseline (56.011 us; speedup 1.0000x reference)
//
#include <hip/hip_runtime.h>

// Problem constants (match reference)
#define NB 8
#define NT 8
#define NO 25
#define NC 3
#define NH 192
#define NW 640
#define NP 16
#define ND 768
#define NGH 12
#define NGW 2
#define NKP (NB*NT*NO)   // 1600 keypoints
#define NK (NC*NP*NP)    // 768 (GEMM K)
#define NTASK (NKP*NC)   // 4800 pool tasks

#define S_STRIDE 41      // odd stride: breaks even-bank stripes on sampling reads

// persistent-pool schedule: 8 XCDs x 84 blocks, 600 tasks per XCD, strided
#define POOL_BLOCKS 672
#define TASKS_PER_XCD 600
#define BLOCKS_PER_XCD 84
// convw: 147456 float4 over 672 blocks
#define CVW_TOTAL ((NK*ND)/4)
#define CVW_PER_BLOCK 220

typedef __attribute__((ext_vector_type(4))) float  f32x4;
typedef __attribute__((ext_vector_type(8))) short  bf16x8;

static __device__ __forceinline__ unsigned short f2bf(float f) {
  union { float f; unsigned u; } x; x.f = f;
  unsigned r = x.u + 0x7FFFu + ((x.u >> 16) & 1u);   // round-to-nearest-even
  return (unsigned short)(r >> 16);
}

// ---------------------------------------------------------------------------
// Per-task geometry (all block-uniform). Math identical to round 4.
// ---------------------------------------------------------------------------
struct TaskGeom {
  const float* src;   // feature plane, pre-offset by rmin*NW
  float start_h, start_w, bin_h, bin_w, sub_h, sub_w, inv_count, inv_nq;
  int n, ch, gh, gw, rmin, cmin_al, nq, nrows, tot;
};

static __device__ __forceinline__ TaskGeom make_geom(
    const float* __restrict__ features, const float* __restrict__ keypoints,
    int t) {
  TaskGeom G;
  G.n  = t / 3;
  G.ch = t - 3 * G.n;
  const float kx = keypoints[G.n * 3 + 0];
  const float ky = keypoints[G.n * 3 + 1];
  const float kr = keypoints[G.n * 3 + 2];
  // Boxes exactly as reference (by2 uses kx — reference quirk, keep it)
  const float bx1 = fmaxf(kx - kr, 0.0f);
  const float by1 = fmaxf(ky - kr, 0.0f);
  const float bx2 = fminf(kx + kr, (float)NW);
  const float by2 = fminf(kx + kr, (float)NH);
  G.start_h = by1 - 0.5f;
  G.start_w = bx1 - 0.5f;
  G.bin_h = (by2 - by1) * (1.0f / (float)NP);
  G.bin_w = (bx2 - bx1) * (1.0f / (float)NP);
  G.gh = (int)ceilf(G.bin_h);           // 1..12
  G.gw = (int)ceilf(G.bin_w);           // 1..2
  const float ghf = (float)max(G.gh, 1);
  const float gwf = (float)max(G.gw, 1);
  G.inv_count = 1.0f / (float)max(G.gh * G.gw, 1);
  G.sub_h = G.bin_h / ghf;
  G.sub_w = G.bin_w / gwf;
  const float cy_min = G.start_h + 0.5f * G.sub_h;
  const float cy_max = G.start_h + 15.0f * G.bin_h + ((float)(G.gh - 1) + 0.5f) * G.sub_h;
  const float cx_min = G.start_w + 0.5f * G.sub_w;
  const float cx_max = G.start_w + 15.0f * G.bin_w + ((float)(G.gw - 1) + 0.5f) * G.sub_w;
  G.rmin = (int)floorf(fminf(fmaxf(cy_min, 0.0f), (float)(NH - 1)));
  const int rmax = min((int)floorf(fminf(fmaxf(cy_max, 0.0f), (float)(NH - 1))) + 1, NH - 1);
  const int cmin = (int)floorf(fminf(fmaxf(cx_min, 0.0f), (float)(NW - 1)));
  const int cmax = min((int)floorf(fminf(fmaxf(cx_max, 0.0f), (float)(NW - 1))) + 1, NW - 1);
  G.nrows = rmax - G.rmin + 1;          // <= 192
  G.cmin_al = cmin & ~3;                // 4-aligned for float4 loads
  G.nq = ((cmax - G.cmin_al) >> 2) + 1; // float4 groups per row, <= 10
  G.tot = G.nrows * G.nq;               // <= 1920
  G.inv_nq = 1.0f / (float)G.nq;
  const int img  = G.n / NO;
  const int bb   = img / NT;
  const int timg = img - bb * NT;
  G.src = features + (size_t)((bb * NC + G.ch) * NT + timg) * (NH * NW)
        + (size_t)G.rmin * NW;
  return G;
}

// ---------------------------------------------------------------------------
// Kernel 1: persistent ROI-align pooling + conv_w convert.
// 672 blocks, each: convw slice (fire-and-forget) + ~7-8 pooling tasks,
// software-pipelined: task k+1's footprint loads are issued (into named
// registers) before sampling task k, hiding the L3 latency behind compute.
// ---------------------------------------------------------------------------
__global__ __launch_bounds__(256) void pool_kernel(
    const float* __restrict__ features,   // [B][C][T][H][W] f32
    const float* __restrict__ keypoints,  // [N][3] (kx, ky, kr)
    const float* __restrict__ conv_w,     // [768][768] f32
    unsigned short* __restrict__ pooled,  // [N][768] bf16
    unsigned short* __restrict__ wbf)     // [768][768] bf16
{
  __shared__ float S[NH * S_STRIDE];      // 192*41*4 = 31488 B

  const int p   = blockIdx.x;
  const int tid = threadIdx.x;

  // --- convw slice: issue load now, store after task-0 loads are issued ---
  const int widx = p * CVW_PER_BLOCK + tid;
  const bool wact = (tid < CVW_PER_BLOCK) && (widx < CVW_TOTAL);
  float4 wv = {};
  if (wact) wv = reinterpret_cast<const float4*>(conv_w)[widx];

  // --- task schedule: XCD x (= p&7) owns tasks [x*600, (x+1)*600), strided ---
  const int xcd = p & 7;
  const int lb  = p >> 3;                 // 0..83
  const int tbase = xcd * TASKS_PER_XCD + lb;
  const int ntasks = (TASKS_PER_XCD - lb + BLOCKS_PER_XCD - 1) / BLOCKS_PER_XCD;

  TaskGeom gc = make_geom(features, keypoints, tbase);

  float4 v0, v1, v2, v3, v4, v5, v6, v7;
  int ro0, ro1, ro2, ro3, ro4, ro5, ro6, ro7;   // LDS float offset, -1 = skip

#define STAGE_LOAD(G, Q, V, RO)                                              \
  {                                                                          \
    const int e = tid + (Q << 8);                                            \
    if (e < G.tot) {                                                         \
      const int r  = (int)(((float)e + 0.5f) * G.inv_nq);                    \
      const int c4 = (e - r * G.nq) << 2;                                    \
      const int gcl = G.cmin_al + c4;                                        \
      const float* pp = G.src + (size_t)r * NW + gcl;                        \
      if (gcl + 3 < NW) { V = *reinterpret_cast<const float4*>(pp); }        \
      else { V.x = pp[0]; V.y = pp[min(1, NW - 1 - gcl)];                    \
             V.z = pp[min(2, NW - 1 - gcl)]; V.w = pp[min(3, NW - 1 - gcl)]; } \
      RO = r * S_STRIDE + c4;                                                \
    } else { RO = -1; }                                                      \
  }
#define STAGE_ALL(G)                                                         \
  STAGE_LOAD(G, 0, v0, ro0) STAGE_LOAD(G, 1, v1, ro1)                        \
  STAGE_LOAD(G, 2, v2, ro2) STAGE_LOAD(G, 3, v3, ro3)                        \
  STAGE_LOAD(G, 4, v4, ro4) STAGE_LOAD(G, 5, v5, ro5)                        \
  STAGE_LOAD(G, 6, v6, ro6) STAGE_LOAD(G, 7, v7, ro7)

#define STAGE_WRITE(V, RO)                                                   \
  if (RO >= 0) { float* s = &S[RO];                                          \
    s[0] = V.x; s[1] = V.y; s[2] = V.z; s[3] = V.w; }
#define STAGE_WRITE_ALL()                                                    \
  STAGE_WRITE(v0, ro0) STAGE_WRITE(v1, ro1) STAGE_WRITE(v2, ro2)             \
  STAGE_WRITE(v3, ro3) STAGE_WRITE(v4, ro4) STAGE_WRITE(v5, ro5)             \
  STAGE_WRITE(v6, ro6) STAGE_WRITE(v7, ro7)

  STAGE_ALL(gc)                           // task-0 loads in flight

  if (wact) {                             // waits only the convw load
    ushort4 o;
    o.x = f2bf(wv.x); o.y = f2bf(wv.y); o.z = f2bf(wv.z); o.w = f2bf(wv.w);
    reinterpret_cast<ushort4*>(wbf)[widx] = o;
  }

  const int i = tid >> 4;
  const int j = tid & 15;

  for (int k = 0; k < ntasks; ++k) {
    const bool more = (k + 1 < ntasks);   // block-uniform
    TaskGeom gn;
    if (more) gn = make_geom(features, keypoints, tbase + (k + 1) * BLOCKS_PER_XCD);

    // write task-k footprint to LDS (waits the in-flight loads)
    STAGE_WRITE_ALL()
    // zero pad column: x0+1 read hits it only when lx==0 (weight 0)
    if (tid < gc.nrows) S[tid * S_STRIDE + (gc.nq << 2)] = 0.0f;
    __syncthreads();

    // issue task-(k+1) loads now — latency hides under sampling below
    if (more) { STAGE_ALL(gn) }

    // --- bilinear sampling of task k (reference formula order) ---
    float lxv[NGW]; int cxv[NGW];
#pragma unroll
    for (int gx = 0; gx < NGW; ++gx) {
      const float c = gc.start_w + (float)j * gc.bin_w + ((float)gx + 0.5f) * gc.sub_w;
      const float cc = fminf(fmaxf(c, 0.0f), (float)(NW - 1));
      const int x0 = (int)floorf(cc);
      lxv[gx] = cc - (float)x0;
      cxv[gx] = x0 - gc.cmin_al;   // x1 = x0+1 implicit (pad col zero, weight 0)
    }

    float acc = 0.0f;
#pragma unroll
    for (int gy = 0; gy < NGH; ++gy) {
      if (gy >= gc.gh) break;            // block-uniform bound
      const float c = gc.start_h + (float)i * gc.bin_h + ((float)gy + 0.5f) * gc.sub_h;
      const float cc = fminf(fmaxf(c, 0.0f), (float)(NH - 1));
      const int y0 = (int)floorf(cc);
      const float ly = cc - (float)y0;
      const float hy = 1.0f - ly;
      const int ry0 = (y0 - gc.rmin) * S_STRIDE;
      const int ry1 = (min(y0 + 1, NH - 1) - gc.rmin) * S_STRIDE;
#pragma unroll
      for (int gx = 0; gx < NGW; ++gx) {
        if (gx >= gc.gw) break;          // block-uniform bound
        const float lx = lxv[gx];
        const float hx = 1.0f - lx;
        const float* r0 = &S[ry0 + cxv[gx]];
        const float* r1 = &S[ry1 + cxv[gx]];
        const float s00 = r0[0], s01 = r0[1];   // -> ds_read2_b32
        const float s10 = r1[0], s11 = r1[1];   // -> ds_read2_b32
        acc += hy * (hx * s00 + lx * s01) + ly * (hx * s10 + lx * s11);
      }
    }
    pooled[(size_t)gc.n * NK + gc.ch * (NP * NP) + tid] = f2bf(acc * gc.inv_count);

    __syncthreads();                     // S reusable for next task
    if (more) gc = gn;
  }
#undef STAGE_ALL
#undef STAGE_LOAD
#undef STAGE_WRITE
#undef STAGE_WRITE_ALL
}

// ---------------------------------------------------------------------------
// Kernel 2: bf16 MFMA GEMM  out[1600][768] = A[1600][768] . Bw[768][768]^T + b
// BM=BN=64, BK=64, grid 25x12=300 blocks, 4 waves (2x2), wave tile 32x32.
// Double-buffered LDS, 2-phase prefetch, XOR-swizzle via pre-swizzled source.
// ---------------------------------------------------------------------------
#define BM 64
#define BN 64
#define BK 64

static __device__ __forceinline__ void gld_lds16(const unsigned short* g,
                                                 unsigned short* l) {
  __builtin_amdgcn_global_load_lds(
      (const __attribute__((address_space(1))) unsigned int*)g,
      (__attribute__((address_space(3))) unsigned int*)l,
      16, 0, 0);
}

__global__ __launch_bounds__(256) void gemm_kernel(
    const unsigned short* __restrict__ A,    // [1600][768] bf16 (pooled)
    const unsigned short* __restrict__ Bw,   // [768][768]  bf16 (conv_w)
    const float* __restrict__ bias,          // [768]
    float* __restrict__ outp)                // [1600][768] f32
{
  __shared__ __align__(16) unsigned short As[2][BM * BK];   // 2 x 8 KB
  __shared__ __align__(16) unsigned short Bs[2][BM * BK];   // 2 x 8 KB

  const int tid = threadIdx.x;
  const int w = tid >> 6;           // wave 0..3
  const int l = tid & 63;           // lane
  const int bm = blockIdx.x * BM;
  const int bn = blockIdx.y * BN;

  const int wr = w >> 1, wc = w & 1;
  const int lr = l & 15;
  const int kh = l >> 4;            // 0..3

  const int rA0 = (wr << 5) + lr;   // A-frag rows (mi=0 / mi=1 = +16)
  const int rB0 = (wc << 5) + lr;   // B-frag rows (= C cols)

#define STAGE(buf, kk)                                                       \
  {                                                                          \
    _Pragma("unroll")                                                        \
    for (int q = 0; q < 2; ++q) {                                            \
      const int s   = (q << 8) + tid;                                        \
      const int row = s >> 3;                                                \
      const int c16 = (s & 7) ^ (row & 7);                                   \
      gld_lds16(A  + (size_t)(bm + row) * NK + (kk) + (c16 << 3),            \
                &As[buf][s << 3]);                                           \
      gld_lds16(Bw + (size_t)(bn + row) * NK + (kk) + (c16 << 3),            \
                &Bs[buf][s << 3]);                                           \
    }                                                                        \
  }

  f32x4 acc[2][2] = {};

  STAGE(0, 0)
  __syncthreads();                  // drains vmcnt(0)

  int cur = 0;
  for (int it = 0; it < NK / BK; ++it) {
    if (it + 1 < NK / BK) STAGE(cur ^ 1, (it + 1) * BK)   // overlap w/ compute

#pragma unroll
    for (int ks = 0; ks < 2; ++ks) {
      const int kq = (ks << 2) + kh;                      // k/8 quad index
      const bf16x8 a0 = *reinterpret_cast<const bf16x8*>(
          &As[cur][(rA0 << 6) + ((kq ^ (rA0 & 7)) << 3)]);
      const bf16x8 a1 = *reinterpret_cast<const bf16x8*>(
          &As[cur][((rA0 + 16) << 6) + ((kq ^ (rA0 & 7)) << 3)]);
      const bf16x8 b0 = *reinterpret_cast<const bf16x8*>(
          &Bs[cur][(rB0 << 6) + ((kq ^ (rB0 & 7)) << 3)]);
      const bf16x8 b1 = *reinterpret_cast<const bf16x8*>(
          &Bs[cur][((rB0 + 16) << 6) + ((kq ^ (rB0 & 7)) << 3)]);
      acc[0][0] = __builtin_amdgcn_mfma_f32_16x16x32_bf16(a0, b0, acc[0][0], 0, 0, 0);
      acc[0][1] = __builtin_amdgcn_mfma_f32_16x16x32_bf16(a0, b1, acc[0][1], 0, 0, 0);
      acc[1][0] = __builtin_amdgcn_mfma_f32_16x16x32_bf16(a1, b0, acc[1][0], 0, 0, 0);
      acc[1][1] = __builtin_amdgcn_mfma_f32_16x16x32_bf16(a1, b1, acc[1][1], 0, 0, 0);
    }

    __syncthreads();                // drains vmcnt (next tile landed) + LDS reuse
    cur ^= 1;
  }
#undef STAGE

  // Epilogue: C/D layout col = lane&15, row = (lane>>4)*4 + reg
#pragma unroll
  for (int ni = 0; ni < 2; ++ni) {
    const int col = bn + (wc << 5) + (ni << 4) + lr;
    const float bv = bias[col];
#pragma unroll
    for (int mi = 0; mi < 2; ++mi) {
      const int rbase = bm + (wr << 5) + (mi << 4) + (kh << 2);
#pragma unroll
      for (int q = 0; q < 4; ++q) {
        outp[(size_t)(rbase + q) * ND + col] = acc[mi][ni][q] + bv;
      }
    }
  }
}

extern "C" void kernel_launch(void* const* d_in, const int* in_sizes, int n_in,
                              void* d_out, int out_size, void* d_ws, size_t ws_size,
                              hipStream_t stream) {
  (void)in_sizes; (void)n_in; (void)out_size; (void)ws_size;
  const float* features  = (const float*)d_in[0];
  const float* keypoints = (const float*)d_in[1];
  const float* conv_w    = (const float*)d_in[2];
  const float* conv_b    = (const float*)d_in[3];
  float* outp = (float*)d_out;

  unsigned short* pooled = (unsigned short*)d_ws;                    // 2,457,600 B
  unsigned short* wbf    = (unsigned short*)((char*)d_ws + 2457600); // 1,179,648 B

  pool_kernel<<<POOL_BLOCKS, 256, 0, stream>>>(features, keypoints, conv_w,
                                               pooled, wbf);

  dim3 grid(NKP / BM, ND / BN);   // 25 x 12 = 300
  gemm_kernel<<<grid, 256, 0, stream>>>(pooled, wbf, conv_b, outp);
}